// Round 1
// baseline (1094.164 us; speedup 1.0000x reference)
//
#include <hip/hip_runtime.h>
#include <math.h>

// Sinkhorn divergence (geomloss 'sinkhorn', debias=True, tensorized) with
// quaternion geodesic cost, B=8, P=2048, D=4.
//
// Strategy: NEVER materialize the 2048x2048 cost matrices (402 MB > L3).
// Recompute cost(i,j) = 2*acos(clip(|<q_i,q_j>|,0,1-1e-6)) on the fly inside
// each softmin pass. 13 sequential passes; each pass fuses the 4 independent
// softmins (f_ba, g_ab, f_aa, g_bb) into one kernel launch.
//
// Per block (256 thr = 4 waves): stage the 2048 column points (32KB) and the
// log2-domain h vector (8KB) into LDS; each wave computes one output row with
// an exact two-pass logsumexp (v_j kept in 32 registers; acos computed once).
// Potentials ping-pong between two 256KB halves of d_ws.

#define BATCH 8
#define NP    2048
#define NPOT  (BATCH * NP)   // 16384 floats per potential array

__global__ __launch_bounds__(256) void sink_pass_kernel(
    const float* __restrict__ x, const float* __restrict__ y,
    const float* __restrict__ wx, const float* __restrict__ wy,
    const float* __restrict__ pot_old, float* __restrict__ pot_new,
    float eps, float c1 /* log2e/eps, 0 for init */,
    float c2 /* 2*log2e/eps */, int use_avg)
{
  const int bid  = blockIdx.x;
  const int s    = bid >> 12;          // softmin type: 0=f_ba 1=g_ab 2=f_aa 3=g_bb
  const int b    = (bid >> 9) & 7;     // batch
  const int i0   = (bid & 511) << 2;   // 4 rows per block
  const int tid  = threadIdx.x;
  const int lane = tid & 63;
  const int wv   = tid >> 6;
  const int i    = i0 + wv;

  __shared__ float4 Pts[NP];   // 32 KB: column-side points
  __shared__ float  Hs[NP];    //  8 KB: h_j in log2 domain

  // Column/row side selection (wave-uniform):
  // s=0: C_xy rows=x cols=y h=log(wy)+g_ab/eps -> f_ba
  // s=1: C_yx rows=y cols=x h=log(wx)+f_ba/eps -> g_ab
  // s=2: C_xx rows=x cols=x h=log(wx)+f_aa/eps -> f_aa
  // s=3: C_yy rows=y cols=y h=log(wy)+g_bb/eps -> g_bb
  const float4* colp; const float* colw; const float* colpot; const float4* rowp;
  if (s == 0)      { colp=(const float4*)y; colw=wy; colpot=pot_old+1*NPOT; rowp=(const float4*)x; }
  else if (s == 1) { colp=(const float4*)x; colw=wx; colpot=pot_old+0*NPOT; rowp=(const float4*)y; }
  else if (s == 2) { colp=(const float4*)x; colw=wx; colpot=pot_old+2*NPOT; rowp=(const float4*)x; }
  else             { colp=(const float4*)y; colw=wy; colpot=pot_old+3*NPOT; rowp=(const float4*)y; }
  colp += b * NP; colw += b * NP; colpot += b * NP;

  #pragma unroll
  for (int t = 0; t < 8; ++t) {
    int idx = tid + t * 256;
    Pts[idx] = colp[idx];
    // h_j * log2(e) = log2(w_j) + pot_j * (log2e/eps). c1==0 on init pass:
    // poison (finite float) * 0 == 0, so no memset needed.
    Hs[idx] = __builtin_amdgcn_logf(colw[idx]) + colpot[idx] * c1;
  }
  __syncthreads();

  const float4 q = rowp[b * NP + i];

  float vbuf[32];
  float m = -3.0e38f;
  #pragma unroll
  for (int t = 0; t < 32; ++t) {
    const int j = t * 64 + lane;
    const float4 p = Pts[j];
    float d = fabsf(q.x * p.x + q.y * p.y + q.z * p.z + q.w * p.w);
    d = fminf(d, 0.999999f);                    // clip(dot, 0, 1-1e-6)
    // acos(d) = sqrt(1-d) * poly(d)   (A&S 4.4.46, |err| <= 2e-8)
    const float sq = __builtin_amdgcn_sqrtf(1.0f - d);
    float pl;
    pl = fmaf(-0.0012624911f, d,  0.0066700901f);
    pl = fmaf(pl, d, -0.0170881256f);
    pl = fmaf(pl, d,  0.0308918810f);
    pl = fmaf(pl, d, -0.0501743046f);
    pl = fmaf(pl, d,  0.0889789874f);
    pl = fmaf(pl, d, -0.2145988016f);
    pl = fmaf(pl, d,  1.5707963050f);
    // v_j = (h_j - C_ij/eps)*log2e ; C = 2*acos -> acos * c2
    const float v = fmaf(sq * pl, -c2, Hs[j]);
    vbuf[t] = v;
    m = fmaxf(m, v);
  }

  #pragma unroll
  for (int off = 32; off >= 1; off >>= 1)
    m = fmaxf(m, __shfl_xor(m, off, 64));

  float ss = 0.0f;
  #pragma unroll
  for (int t = 0; t < 32; ++t)
    ss += __builtin_amdgcn_exp2f(vbuf[t] - m);
  #pragma unroll
  for (int off = 32; off >= 1; off >>= 1)
    ss += __shfl_xor(ss, off, 64);

  if (lane == 0) {
    // softmin = -eps * ln(sum) = -eps * ln2 * (m + log2(ss))
    float res = -eps * 0.69314718055994531f * (m + __builtin_amdgcn_logf(ss));
    const int oidx = s * NPOT + b * NP + i;
    if (use_avg) res = 0.5f * (pot_old[oidx] + res);
    pot_new[oidx] = res;
  }
}

__global__ __launch_bounds__(256) void loss_kernel(
    const float* __restrict__ pot, const float* __restrict__ wx,
    const float* __restrict__ wy, float* __restrict__ out)
{
  const int tid = threadIdx.x;
  double acc = 0.0;
  for (int idx = tid; idx < NPOT; idx += 256) {
    acc += (double)wx[idx] * ((double)pot[0 * NPOT + idx] - (double)pot[2 * NPOT + idx]);
    acc += (double)wy[idx] * ((double)pot[1 * NPOT + idx] - (double)pot[3 * NPOT + idx]);
  }
  #pragma unroll
  for (int off = 32; off >= 1; off >>= 1)
    acc += __shfl_xor(acc, off, 64);
  __shared__ double wsum[4];
  if ((tid & 63) == 0) wsum[tid >> 6] = acc;
  __syncthreads();
  if (tid == 0)
    out[0] = (float)((wsum[0] + wsum[1] + wsum[2] + wsum[3]) / (double)BATCH);
}

extern "C" void kernel_launch(void* const* d_in, const int* in_sizes, int n_in,
                              void* d_out, int out_size, void* d_ws, size_t ws_size,
                              hipStream_t stream)
{
  const float* x  = (const float*)d_in[0];
  const float* y  = (const float*)d_in[1];
  const float* wx = (const float*)d_in[2];
  const float* wy = (const float*)d_in[3];

  float* pot[2];
  pot[0] = (float*)d_ws;          // 4 arrays of 16384 floats (256 KB)
  pot[1] = pot[0] + 4 * NPOT;     // ping-pong set (512 KB total in ws)

  // geomloss epsilon_schedule(p=2, diameter=3.15, blur=0.01, scaling=0.5)
  double eps_list[16]; int ne = 0;
  eps_list[ne++] = 3.15 * 3.15;
  const double stop = 2.0 * log(0.01), step = 2.0 * log(0.5);
  for (double e = 2.0 * log(3.15); e > stop; e += step) eps_list[ne++] = exp(e);
  eps_list[ne++] = 0.01 * 0.01;   // ne == 11

  const double LOG2E = 1.4426950408889634;
  const dim3 grid(16384), blk(256);
  int cur = 0;

  // init pass: h has no potential term (c1 = 0), replace-mode
  {
    const double e = eps_list[0];
    hipLaunchKernelGGL(sink_pass_kernel, grid, blk, 0, stream,
        x, y, wx, wy, pot[cur], pot[1 - cur],
        (float)e, 0.0f, (float)(2.0 * LOG2E / e), 0);
    cur ^= 1;
  }
  // annealing loop over ALL eps in the schedule, averaging update
  for (int k = 0; k < ne; ++k) {
    const double e = eps_list[k];
    hipLaunchKernelGGL(sink_pass_kernel, grid, blk, 0, stream,
        x, y, wx, wy, pot[cur], pot[1 - cur],
        (float)e, (float)(LOG2E / e), (float)(2.0 * LOG2E / e), 1);
    cur ^= 1;
  }
  // final extrapolation at eps = blur^p, replace-mode
  {
    const double e = eps_list[ne - 1];
    hipLaunchKernelGGL(sink_pass_kernel, grid, blk, 0, stream,
        x, y, wx, wy, pot[cur], pot[1 - cur],
        (float)e, (float)(LOG2E / e), (float)(2.0 * LOG2E / e), 0);
    cur ^= 1;
  }

  hipLaunchKernelGGL(loss_kernel, dim3(1), blk, 0, stream,
      pot[cur], wx, wy, (float*)d_out);
}

// Round 2
// 1085.032 us; speedup vs baseline: 1.0084x; 1.0084x over previous
//
#include <hip/hip_runtime.h>
#include <math.h>

// Sinkhorn divergence (geomloss 'sinkhorn', debias=True) with quaternion
// geodesic cost, B=8, P=2048, D=4.
//
// R2: the cost matrices are identical across all 13 passes (only h changes).
// Precompute C_xy, C_yx, C_xx, C_yy once as u16 fixed-point (err 2.4e-5)
// into d_ws (268 MB), turning each VALU-bound pass (93.6 us) into a
// memory-streaming pass (~45 us). Falls back to the verified recompute
// kernels if ws_size is too small.

#define BATCH 8
#define NP    2048
#define NPOT  (BATCH * NP)                 // 16384 floats per potential array
#define MATU  (BATCH * NP * NP / 2)        // uints per u16 matrix = 16,777,216
#define MATB  ((size_t)BATCH * NP * NP * 2) // bytes per matrix = 67,108,864

// ---------------------------------------------------------------------------
// Materialized path
// ---------------------------------------------------------------------------

__global__ __launch_bounds__(256) void precompute_kernel(
    const float* __restrict__ x, const float* __restrict__ y,
    unsigned int* __restrict__ ws)
{
  // grid = BATCH * 2080 blocks; per batch: 1024 xy tiles (full 32x32 grid of
  // 64x64 tiles) + 528 lower-tri tiles for xx + 528 for yy (symmetric:
  // write tile + its transpose).
  const int bid = blockIdx.x;
  const int b   = bid / 2080;
  const int t   = bid - b * 2080;
  int m, ti, tj;
  if (t < 1024) { m = 0; ti = t >> 5; tj = t & 31; }
  else {
    int ts = t - 1024;
    m = 1 + (ts >= 528);
    int u = ts - (m - 1) * 528;
    int a = (int)((sqrtf(8.0f * (float)u + 1.0f) - 1.0f) * 0.5f);
    while ((a + 1) * (a + 2) / 2 <= u) ++a;
    while (a * (a + 1) / 2 > u) --a;
    ti = a; tj = u - a * (a + 1) / 2;   // tj <= ti (lower triangle)
  }

  unsigned int* Cxy = ws;
  unsigned int* Cyx = ws + 1 * MATU;
  unsigned int* Cxx = ws + 2 * MATU;
  unsigned int* Cyy = ws + 3 * MATU;
  const float4* rowp; const float4* colp; unsigned int *outN, *outT;
  if (m == 0)      { rowp = (const float4*)x; colp = (const float4*)y; outN = Cxy; outT = Cyx; }
  else if (m == 1) { rowp = (const float4*)x; colp = rowp;             outN = Cxx; outT = Cxx; }
  else             { rowp = (const float4*)y; colp = rowp;             outN = Cyy; outT = Cyy; }
  rowp += b * NP; colp += b * NP;

  __shared__ float4 Rq[64];
  __shared__ float4 Cq[64];
  __shared__ unsigned short T[64 * 66];   // +2 pad per row

  const int tid = threadIdx.x;
  if (tid < 64)       Rq[tid]      = rowp[ti * 64 + tid];
  else if (tid < 128) Cq[tid - 64] = colp[tj * 64 + (tid - 64)];
  __syncthreads();

  const int lane = tid & 63, w = tid >> 6;
  const float4 cq = Cq[lane];
  const float S = 65535.0f / 3.14159265358979f;
  #pragma unroll
  for (int k = 0; k < 16; ++k) {
    const int a = 4 * k + w;                 // row within tile (wave-uniform)
    const float4 rq = Rq[a];
    float d = fabsf(rq.x * cq.x + rq.y * cq.y + rq.z * cq.z + rq.w * cq.w);
    d = fminf(d, 0.999999f);                 // clip(dot, 0, 1-1e-6)
    const float sq = __builtin_amdgcn_sqrtf(1.0f - d);
    float pl;                                // acos = sqrt(1-d)*poly, |err|<=2e-8
    pl = fmaf(-0.0012624911f, d,  0.0066700901f);
    pl = fmaf(pl, d, -0.0170881256f);
    pl = fmaf(pl, d,  0.0308918810f);
    pl = fmaf(pl, d, -0.0501743046f);
    pl = fmaf(pl, d,  0.0889789874f);
    pl = fmaf(pl, d, -0.2145988016f);
    pl = fmaf(pl, d,  1.5707963050f);
    const float C = 2.0f * sq * pl;          // [0, pi]
    T[a * 66 + lane] = (unsigned short)(fmaf(C, S, 0.5f));
  }
  __syncthreads();

  const size_t baseN = (size_t)b * NP * 1024;
  // normal (row-major) write of the tile, 2 cols packed per uint
  #pragma unroll
  for (int k = 0; k < 8; ++k) {
    const int u = k * 256 + tid;
    const int a = u >> 5, p = u & 31;
    const unsigned int val = (unsigned int)T[a * 66 + 2 * p]
                           | ((unsigned int)T[a * 66 + 2 * p + 1] << 16);
    outN[baseN + (size_t)(ti * 64 + a) * 1024 + tj * 32 + p] = val;
  }
  // transposed write (xy -> Cyx; symmetric -> same matrix, mirrored tile)
  #pragma unroll
  for (int k = 0; k < 8; ++k) {
    const int u = k * 256 + tid;
    const int r = u >> 5, p = u & 31;
    const unsigned int val = (unsigned int)T[(2 * p) * 66 + r]
                           | ((unsigned int)T[(2 * p + 1) * 66 + r] << 16);
    outT[baseN + (size_t)(tj * 64 + r) * 1024 + ti * 32 + p] = val;
  }
}

__global__ __launch_bounds__(256) void sink_pass_mat(
    const unsigned int* __restrict__ mats,
    const float* __restrict__ wx, const float* __restrict__ wy,
    const float* __restrict__ pot_old, float* __restrict__ pot_new,
    float eps, float c1 /* log2e/eps, 0 on init */,
    float kdec /* (pi/65535)*log2e/eps */, int use_avg)
{
  const int bid  = blockIdx.x;
  const int s    = bid >> 12;          // 0=f_ba(Cxy) 1=g_ab(Cyx) 2=f_aa(Cxx) 3=g_bb(Cyy)
  const int b    = (bid >> 9) & 7;
  const int i0   = (bid & 511) << 2;
  const int tid  = threadIdx.x;
  const int lane = tid & 63;
  const int wv   = tid >> 6;
  const int i    = i0 + wv;

  __shared__ float Hs[NP];

  const float* colw; const float* colpot;
  if (s == 0)      { colw = wy; colpot = pot_old + 1 * NPOT; }
  else if (s == 1) { colw = wx; colpot = pot_old + 0 * NPOT; }
  else if (s == 2) { colw = wx; colpot = pot_old + 2 * NPOT; }
  else             { colw = wy; colpot = pot_old + 3 * NPOT; }
  colw += b * NP; colpot += b * NP;

  #pragma unroll
  for (int t = 0; t < 8; ++t) {
    const int idx = tid + t * 256;
    Hs[idx] = __builtin_amdgcn_logf(colw[idx]) + colpot[idx] * c1;
  }
  __syncthreads();

  const unsigned int* row = mats + (size_t)s * MATU + ((size_t)(b * NP + i) << 10);

  float vbuf[32];
  float mx = -3.0e38f;
  #pragma unroll
  for (int t = 0; t < 16; ++t) {
    const unsigned int U = row[t * 64 + lane];        // 2 packed u16 costs
    const int j = t * 128 + 2 * lane;
    const float2 h = *(const float2*)&Hs[j];          // ds_read_b64, 2-way ok
    const float v0 = fmaf((float)(U & 0xFFFFu), -kdec, h.x);
    const float v1 = fmaf((float)(U >> 16),     -kdec, h.y);
    vbuf[2 * t]     = v0;
    vbuf[2 * t + 1] = v1;
    mx = fmaxf(mx, fmaxf(v0, v1));
  }

  #pragma unroll
  for (int off = 32; off >= 1; off >>= 1)
    mx = fmaxf(mx, __shfl_xor(mx, off, 64));

  float ss = 0.0f;
  #pragma unroll
  for (int t = 0; t < 32; ++t)
    ss += __builtin_amdgcn_exp2f(vbuf[t] - mx);
  #pragma unroll
  for (int off = 32; off >= 1; off >>= 1)
    ss += __shfl_xor(ss, off, 64);

  if (lane == 0) {
    float res = -eps * 0.69314718055994531f * (mx + __builtin_amdgcn_logf(ss));
    const int oidx = s * NPOT + b * NP + i;
    if (use_avg) res = 0.5f * (pot_old[oidx] + res);
    pot_new[oidx] = res;
  }
}

// ---------------------------------------------------------------------------
// Fallback path (verified R1 recompute kernel, unchanged)
// ---------------------------------------------------------------------------

__global__ __launch_bounds__(256) void sink_pass_kernel(
    const float* __restrict__ x, const float* __restrict__ y,
    const float* __restrict__ wx, const float* __restrict__ wy,
    const float* __restrict__ pot_old, float* __restrict__ pot_new,
    float eps, float c1, float c2, int use_avg)
{
  const int bid  = blockIdx.x;
  const int s    = bid >> 12;
  const int b    = (bid >> 9) & 7;
  const int i0   = (bid & 511) << 2;
  const int tid  = threadIdx.x;
  const int lane = tid & 63;
  const int wv   = tid >> 6;
  const int i    = i0 + wv;

  __shared__ float4 Pts[NP];
  __shared__ float  Hs[NP];

  const float4* colp; const float* colw; const float* colpot; const float4* rowp;
  if (s == 0)      { colp=(const float4*)y; colw=wy; colpot=pot_old+1*NPOT; rowp=(const float4*)x; }
  else if (s == 1) { colp=(const float4*)x; colw=wx; colpot=pot_old+0*NPOT; rowp=(const float4*)y; }
  else if (s == 2) { colp=(const float4*)x; colw=wx; colpot=pot_old+2*NPOT; rowp=(const float4*)x; }
  else             { colp=(const float4*)y; colw=wy; colpot=pot_old+3*NPOT; rowp=(const float4*)y; }
  colp += b * NP; colw += b * NP; colpot += b * NP;

  #pragma unroll
  for (int t = 0; t < 8; ++t) {
    int idx = tid + t * 256;
    Pts[idx] = colp[idx];
    Hs[idx] = __builtin_amdgcn_logf(colw[idx]) + colpot[idx] * c1;
  }
  __syncthreads();

  const float4 q = rowp[b * NP + i];

  float vbuf[32];
  float m = -3.0e38f;
  #pragma unroll
  for (int t = 0; t < 32; ++t) {
    const int j = t * 64 + lane;
    const float4 p = Pts[j];
    float d = fabsf(q.x * p.x + q.y * p.y + q.z * p.z + q.w * p.w);
    d = fminf(d, 0.999999f);
    const float sq = __builtin_amdgcn_sqrtf(1.0f - d);
    float pl;
    pl = fmaf(-0.0012624911f, d,  0.0066700901f);
    pl = fmaf(pl, d, -0.0170881256f);
    pl = fmaf(pl, d,  0.0308918810f);
    pl = fmaf(pl, d, -0.0501743046f);
    pl = fmaf(pl, d,  0.0889789874f);
    pl = fmaf(pl, d, -0.2145988016f);
    pl = fmaf(pl, d,  1.5707963050f);
    const float v = fmaf(sq * pl, -c2, Hs[j]);
    vbuf[t] = v;
    m = fmaxf(m, v);
  }

  #pragma unroll
  for (int off = 32; off >= 1; off >>= 1)
    m = fmaxf(m, __shfl_xor(m, off, 64));

  float ss = 0.0f;
  #pragma unroll
  for (int t = 0; t < 32; ++t)
    ss += __builtin_amdgcn_exp2f(vbuf[t] - m);
  #pragma unroll
  for (int off = 32; off >= 1; off >>= 1)
    ss += __shfl_xor(ss, off, 64);

  if (lane == 0) {
    float res = -eps * 0.69314718055994531f * (m + __builtin_amdgcn_logf(ss));
    const int oidx = s * NPOT + b * NP + i;
    if (use_avg) res = 0.5f * (pot_old[oidx] + res);
    pot_new[oidx] = res;
  }
}

// ---------------------------------------------------------------------------

__global__ __launch_bounds__(256) void loss_kernel(
    const float* __restrict__ pot, const float* __restrict__ wx,
    const float* __restrict__ wy, float* __restrict__ out)
{
  const int tid = threadIdx.x;
  double acc = 0.0;
  for (int idx = tid; idx < NPOT; idx += 256) {
    acc += (double)wx[idx] * ((double)pot[0 * NPOT + idx] - (double)pot[2 * NPOT + idx]);
    acc += (double)wy[idx] * ((double)pot[1 * NPOT + idx] - (double)pot[3 * NPOT + idx]);
  }
  #pragma unroll
  for (int off = 32; off >= 1; off >>= 1)
    acc += __shfl_xor(acc, off, 64);
  __shared__ double wsum[4];
  if ((tid & 63) == 0) wsum[tid >> 6] = acc;
  __syncthreads();
  if (tid == 0)
    out[0] = (float)((wsum[0] + wsum[1] + wsum[2] + wsum[3]) / (double)BATCH);
}

extern "C" void kernel_launch(void* const* d_in, const int* in_sizes, int n_in,
                              void* d_out, int out_size, void* d_ws, size_t ws_size,
                              hipStream_t stream)
{
  const float* x  = (const float*)d_in[0];
  const float* y  = (const float*)d_in[1];
  const float* wx = (const float*)d_in[2];
  const float* wy = (const float*)d_in[3];

  const size_t REQ_WS = 4 * MATB + 2 * (size_t)4 * NPOT * 4;  // 268,959,744
  const bool use_mat = (ws_size >= REQ_WS);

  float* pot[2];
  if (use_mat) pot[0] = (float*)((char*)d_ws + 4 * MATB);
  else         pot[0] = (float*)d_ws;
  pot[1] = pot[0] + 4 * NPOT;

  // geomloss epsilon_schedule(p=2, diameter=3.15, blur=0.01, scaling=0.5)
  double eps_list[16]; int ne = 0;
  eps_list[ne++] = 3.15 * 3.15;
  const double stop = 2.0 * log(0.01), step = 2.0 * log(0.5);
  for (double e = 2.0 * log(3.15); e > stop; e += step) eps_list[ne++] = exp(e);
  eps_list[ne++] = 0.01 * 0.01;   // ne == 11

  const double LOG2E = 1.4426950408889634;
  const double KU    = 3.14159265358979323846 / 65535.0;   // u16 decode scale
  const dim3 grid(16384), blk(256);
  int cur = 0;

  if (use_mat) {
    unsigned int* mats = (unsigned int*)d_ws;
    hipLaunchKernelGGL(precompute_kernel, dim3(BATCH * 2080), blk, 0, stream,
                       x, y, mats);
    // init pass: no potential in h (c1 = 0), replace-mode
    {
      const double e = eps_list[0];
      hipLaunchKernelGGL(sink_pass_mat, grid, blk, 0, stream,
          mats, wx, wy, pot[cur], pot[1 - cur],
          (float)e, 0.0f, (float)(KU * LOG2E / e), 0);
      cur ^= 1;
    }
    for (int k = 0; k < ne; ++k) {
      const double e = eps_list[k];
      hipLaunchKernelGGL(sink_pass_mat, grid, blk, 0, stream,
          mats, wx, wy, pot[cur], pot[1 - cur],
          (float)e, (float)(LOG2E / e), (float)(KU * LOG2E / e), 1);
      cur ^= 1;
    }
    {
      const double e = eps_list[ne - 1];
      hipLaunchKernelGGL(sink_pass_mat, grid, blk, 0, stream,
          mats, wx, wy, pot[cur], pot[1 - cur],
          (float)e, (float)(LOG2E / e), (float)(KU * LOG2E / e), 0);
      cur ^= 1;
    }
  } else {
    {
      const double e = eps_list[0];
      hipLaunchKernelGGL(sink_pass_kernel, grid, blk, 0, stream,
          x, y, wx, wy, pot[cur], pot[1 - cur],
          (float)e, 0.0f, (float)(2.0 * LOG2E / e), 0);
      cur ^= 1;
    }
    for (int k = 0; k < ne; ++k) {
      const double e = eps_list[k];
      hipLaunchKernelGGL(sink_pass_kernel, grid, blk, 0, stream,
          x, y, wx, wy, pot[cur], pot[1 - cur],
          (float)e, (float)(LOG2E / e), (float)(2.0 * LOG2E / e), 1);
      cur ^= 1;
    }
    {
      const double e = eps_list[ne - 1];
      hipLaunchKernelGGL(sink_pass_kernel, grid, blk, 0, stream,
          x, y, wx, wy, pot[cur], pot[1 - cur],
          (float)e, (float)(LOG2E / e), (float)(2.0 * LOG2E / e), 0);
      cur ^= 1;
    }
  }

  hipLaunchKernelGGL(loss_kernel, dim3(1), blk, 0, stream,
      pot[cur], wx, wy, (float*)d_out);
}

// Round 3
// 991.127 us; speedup vs baseline: 1.1040x; 1.0947x over previous
//
#include <hip/hip_runtime.h>
#include <math.h>

// Sinkhorn divergence (geomloss 'sinkhorn', debias=True) with quaternion
// geodesic cost, B=8, P=2048, D=4.
//
// R3: R1/R2 profiling showed the recompute pass serializes VALU (44us) with
// LDS traffic (51us, 20B/elem). This version removes ALL LDS/DS from the hot
// loop: each lane owns one row; the column stream (quat + h) is wave-uniform,
// fetched via the scalar pipe (s_load) and v_readlane broadcast. Row softmin
// uses chunked online-logsumexp (chunk=8, exact rescale). acos poly deg-3
// (A&S 4.4.45, err 6.7e-5 -> loss err ~3e-4 << 4.35e-3 threshold), with the
// 2*log2e/eps scale folded into the coefficients at launch time.
// ws usage: pot ping-pong only (512 KB, proven safe in R1).

#define BATCH 8
#define NP    2048
#define NPOT  (BATCH * NP)   // 16384 floats per potential array

__global__ __launch_bounds__(256) void sink_pass_u(
    const float* __restrict__ x, const float* __restrict__ y,
    const float* __restrict__ wx, const float* __restrict__ wy,
    const float* __restrict__ pot_old, float* __restrict__ pot_new,
    float eps, float c1 /* log2e/eps, 0 on init */,
    float A0, float A1, float A2, float A3 /* acos poly * 2*log2e/eps */,
    int use_avg)
{
  // grid = 1024 blocks: s (4) x b (8) x rowgroup (32). Block = 4 waves, all
  // covering the same 64 rows; wave wv handles column quarter [wv*512, ...).
  const int bid  = blockIdx.x;
  const int s    = bid >> 8;           // 0=f_ba 1=g_ab 2=f_aa 3=g_bb
  const int b    = (bid >> 5) & 7;
  const int rg   = bid & 31;
  const int tid  = threadIdx.x;
  const int lane = tid & 63;
  const int wv   = tid >> 6;
  const int i    = rg * 64 + lane;     // this lane's row

  // Stream selection (block-uniform):
  // s=0: C_xy rows=x cols=y h=log(wy)+g_ab/eps   s=1: C_yx rows=y cols=x h=..f_ba
  // s=2: C_xx rows=x cols=x h=..f_aa             s=3: C_yy rows=y cols=y h=..g_bb
  const float4* colp; const float* colw; const float* colpot; const float4* rowp;
  if (s == 0)      { colp=(const float4*)y; colw=wy; colpot=pot_old+1*NPOT; rowp=(const float4*)x; }
  else if (s == 1) { colp=(const float4*)x; colw=wx; colpot=pot_old+0*NPOT; rowp=(const float4*)y; }
  else if (s == 2) { colp=(const float4*)x; colw=wx; colpot=pot_old+2*NPOT; rowp=(const float4*)x; }
  else             { colp=(const float4*)y; colw=wy; colpot=pot_old+3*NPOT; rowp=(const float4*)y; }
  colp += b * NP; colw += b * NP; colpot += b * NP;

  const float4 q = rowp[b * NP + i];   // per-lane row quaternion (coalesced)

  const int j0 = wv * 512;
  float m  = -3.0e38f;
  float ss = 0.0f;

  for (int sc = 0; sc < 8; ++sc) {     // 8 superchunks of 64 columns
    const int jb = j0 + sc * 64;
    // Cooperative h for this superchunk: lane u computes h[jb+u]; broadcast
    // below via v_readlane (no LDS, no lgkm coupling).
    const float hv = fmaf(colpot[jb + lane], c1,
                          __builtin_amdgcn_logf(colw[jb + lane]));
    #pragma unroll
    for (int g = 0; g < 8; ++g) {      // groups of 8 columns
      float vv[8];
      float cm = -3.0e38f;
      #pragma unroll
      for (int u = 0; u < 8; ++u) {
        const int j = jb + g * 8 + u;
        const float4 p = colp[j];      // wave-uniform -> scalar load
        const float h = __int_as_float(
            __builtin_amdgcn_readlane(__float_as_int(hv), g * 8 + u));
        const float dt = fmaf(q.x, p.x, fmaf(q.y, p.y, fmaf(q.z, p.z, q.w * p.w)));
        const float d  = fminf(fabsf(dt), 0.999999f);   // clip(|dot|, 1-1e-6)
        const float sq = __builtin_amdgcn_sqrtf(1.0f - d);
        // scaled acos: pl = (2*log2e/eps) * (a0 + a1 d + a2 d^2 + a3 d^3)
        const float pl = fmaf(fmaf(fmaf(A3, d, A2), d, A1), d, A0);
        const float v  = fmaf(sq, -pl, h);  // h - (C/eps)*log2e
        vv[u] = v;
        cm = fmaxf(cm, v);
      }
      const float mn = fmaxf(m, cm);
      ss = ss * __builtin_amdgcn_exp2f(m - mn);
      #pragma unroll
      for (int u = 0; u < 8; ++u)
        ss += __builtin_amdgcn_exp2f(vv[u] - mn);
      m = mn;
    }
  }

  // Cross-wave merge (4 column quarters of the same row) through 2 KB LDS.
  __shared__ float Ms[4][64];
  __shared__ float Ss[4][64];
  Ms[wv][lane] = m;
  Ss[wv][lane] = ss;
  __syncthreads();
  if (wv == 0) {
    const float m0 = Ms[0][lane], m1 = Ms[1][lane], m2 = Ms[2][lane], m3 = Ms[3][lane];
    const float mt = fmaxf(fmaxf(m0, m1), fmaxf(m2, m3));
    const float st = Ss[0][lane] * __builtin_amdgcn_exp2f(m0 - mt)
                   + Ss[1][lane] * __builtin_amdgcn_exp2f(m1 - mt)
                   + Ss[2][lane] * __builtin_amdgcn_exp2f(m2 - mt)
                   + Ss[3][lane] * __builtin_amdgcn_exp2f(m3 - mt);
    // softmin = -eps * ln2 * (m + log2(sum))
    float res = -eps * 0.69314718055994531f * (mt + __builtin_amdgcn_logf(st));
    const int oidx = s * NPOT + b * NP + i;
    if (use_avg) res = 0.5f * (pot_old[oidx] + res);
    pot_new[oidx] = res;
  }
}

__global__ __launch_bounds__(256) void loss_kernel(
    const float* __restrict__ pot, const float* __restrict__ wx,
    const float* __restrict__ wy, float* __restrict__ out)
{
  const int tid = threadIdx.x;
  double acc = 0.0;
  for (int idx = tid; idx < NPOT; idx += 256) {
    acc += (double)wx[idx] * ((double)pot[0 * NPOT + idx] - (double)pot[2 * NPOT + idx]);
    acc += (double)wy[idx] * ((double)pot[1 * NPOT + idx] - (double)pot[3 * NPOT + idx]);
  }
  #pragma unroll
  for (int off = 32; off >= 1; off >>= 1)
    acc += __shfl_xor(acc, off, 64);
  __shared__ double wsum[4];
  if ((tid & 63) == 0) wsum[tid >> 6] = acc;
  __syncthreads();
  if (tid == 0)
    out[0] = (float)((wsum[0] + wsum[1] + wsum[2] + wsum[3]) / (double)BATCH);
}

extern "C" void kernel_launch(void* const* d_in, const int* in_sizes, int n_in,
                              void* d_out, int out_size, void* d_ws, size_t ws_size,
                              hipStream_t stream)
{
  const float* x  = (const float*)d_in[0];
  const float* y  = (const float*)d_in[1];
  const float* wx = (const float*)d_in[2];
  const float* wy = (const float*)d_in[3];

  float* pot[2];
  pot[0] = (float*)d_ws;          // 4 arrays of 16384 floats (256 KB)
  pot[1] = pot[0] + 4 * NPOT;     // ping-pong set (512 KB total, proven safe)

  // geomloss epsilon_schedule(p=2, diameter=3.15, blur=0.01, scaling=0.5)
  double eps_list[16]; int ne = 0;
  eps_list[ne++] = 3.15 * 3.15;
  const double stop = 2.0 * log(0.01), step = 2.0 * log(0.5);
  for (double e = 2.0 * log(3.15); e > stop; e += step) eps_list[ne++] = exp(e);
  eps_list[ne++] = 0.01 * 0.01;   // ne == 11

  const double LOG2E = 1.4426950408889634;
  // acos(d) ~= sqrt(1-d)*(a0 + a1 d + a2 d^2 + a3 d^3), |err| <= 6.7e-5
  const double a0 = 1.5707288, a1 = -0.2121144, a2 = 0.0742610, a3 = -0.0187293;
  const dim3 grid(1024), blk(256);
  int cur = 0;

  // init pass: h has no potential term (c1 = 0), replace-mode
  {
    const double e = eps_list[0];
    const double sc = 2.0 * LOG2E / e;
    hipLaunchKernelGGL(sink_pass_u, grid, blk, 0, stream,
        x, y, wx, wy, pot[cur], pot[1 - cur],
        (float)e, 0.0f,
        (float)(a0 * sc), (float)(a1 * sc), (float)(a2 * sc), (float)(a3 * sc), 0);
    cur ^= 1;
  }
  // annealing loop over ALL eps in the schedule, averaging update
  for (int k = 0; k < ne; ++k) {
    const double e = eps_list[k];
    const double sc = 2.0 * LOG2E / e;
    hipLaunchKernelGGL(sink_pass_u, grid, blk, 0, stream,
        x, y, wx, wy, pot[cur], pot[1 - cur],
        (float)e, (float)(LOG2E / e),
        (float)(a0 * sc), (float)(a1 * sc), (float)(a2 * sc), (float)(a3 * sc), 1);
    cur ^= 1;
  }
  // final extrapolation at eps = blur^p, replace-mode
  {
    const double e = eps_list[ne - 1];
    const double sc = 2.0 * LOG2E / e;
    hipLaunchKernelGGL(sink_pass_u, grid, blk, 0, stream,
        x, y, wx, wy, pot[cur], pot[1 - cur],
        (float)e, (float)(LOG2E / e),
        (float)(a0 * sc), (float)(a1 * sc), (float)(a2 * sc), (float)(a3 * sc), 0);
    cur ^= 1;
  }

  hipLaunchKernelGGL(loss_kernel, dim3(1), blk, 0, stream,
      pot[cur], wx, wy, (float*)d_out);
}

// Round 5
// 897.572 us; speedup vs baseline: 1.2190x; 1.1042x over previous
//
#include <hip/hip_runtime.h>
#include <math.h>

// Sinkhorn divergence (geomloss 'sinkhorn', debias=True) with quaternion
// geodesic cost, B=8, P=2048, D=4.
//
// R5 = R4 with the launch bug fixed: loss_kernel (launch_bounds 256) was
// being launched with 512 threads -> invalid config -> d_out stayed 0.
// Pass kernel unchanged: block = 512 thr (8 waves), LDS-stage all 2048
// columns (40 KB -> 4 blocks/CU = 32 waves/CU); each wave owns 4 rows with
// row quaternions broadcast to SGPRs; each LDS column read (ds_read_b128 +
// b32, conflict-free) amortized over 4 row-elements. Chunked online
// logsumexp; butterfly merge. acos deg-3 poly (A&S 4.4.45, err 6.7e-5 ->
// loss err ~3e-4 << 4.35e-3 threshold) with 2*log2e/eps folded in.

#define BATCH 8
#define NP    2048
#define NPOT  (BATCH * NP)   // 16384 floats per potential array

__device__ __forceinline__ float bcastf(float v) {
  return __int_as_float(__builtin_amdgcn_readfirstlane(__float_as_int(v)));
}

__global__ __launch_bounds__(512, 8) void sink_pass_r4(
    const float* __restrict__ x, const float* __restrict__ y,
    const float* __restrict__ wx, const float* __restrict__ wy,
    const float* __restrict__ pot_old, float* __restrict__ pot_new,
    float eps, float c1 /* log2e/eps, 0 on init */,
    float A0, float A1, float A2, float A3 /* acos poly * 2*log2e/eps */,
    int use_avg)
{
  // grid = 2048 blocks: s (4) x b (8) x rowgroup (64 of 32 rows each).
  const int bid  = blockIdx.x;
  const int s    = bid >> 9;           // 0=f_ba 1=g_ab 2=f_aa 3=g_bb
  const int b    = (bid >> 6) & 7;
  const int rg   = bid & 63;
  const int tid  = threadIdx.x;
  const int lane = tid & 63;

  __shared__ float4 Pts[NP];   // 32 KB
  __shared__ float  Hs[NP];    //  8 KB

  // Stream selection (block-uniform):
  const float4* colp; const float* colw; const float* colpot; const float4* rowp;
  if (s == 0)      { colp=(const float4*)y; colw=wy; colpot=pot_old+1*NPOT; rowp=(const float4*)x; }
  else if (s == 1) { colp=(const float4*)x; colw=wx; colpot=pot_old+0*NPOT; rowp=(const float4*)y; }
  else if (s == 2) { colp=(const float4*)x; colw=wx; colpot=pot_old+2*NPOT; rowp=(const float4*)x; }
  else             { colp=(const float4*)y; colw=wy; colpot=pot_old+3*NPOT; rowp=(const float4*)y; }
  colp += b * NP; colw += b * NP; colpot += b * NP;

  #pragma unroll
  for (int t = 0; t < 4; ++t) {
    const int idx = tid + t * 512;
    Pts[idx] = colp[idx];
    // h_j in log2 domain. c1==0 on init: poison*0 == 0, no memset needed.
    Hs[idx] = fmaf(colpot[idx], c1, __builtin_amdgcn_logf(colw[idx]));
  }
  __syncthreads();

  // This wave's 4 rows; quaternions broadcast into SGPRs.
  const int wvu = __builtin_amdgcn_readfirstlane(tid >> 6);
  const int i0  = rg * 32 + wvu * 4;
  float4 q[4];
  #pragma unroll
  for (int r = 0; r < 4; ++r) {
    float4 t4 = rowp[b * NP + i0 + r];
    q[r].x = bcastf(t4.x); q[r].y = bcastf(t4.y);
    q[r].z = bcastf(t4.z); q[r].w = bcastf(t4.w);
  }

  float m[4]  = {-3.0e38f, -3.0e38f, -3.0e38f, -3.0e38f};
  float ac[4] = {0.0f, 0.0f, 0.0f, 0.0f};

  for (int t = 0; t < 8; ++t) {        // 8 groups x 4 chunks x 64 lanes = 2048 cols
    float4 p[4]; float h[4];
    #pragma unroll
    for (int c = 0; c < 4; ++c) {
      const int j = (t * 4 + c) * 64 + lane;
      p[c] = Pts[j];
      h[c] = Hs[j];
    }
    #pragma unroll
    for (int r = 0; r < 4; ++r) {
      float v[4];
      #pragma unroll
      for (int c = 0; c < 4; ++c) {
        const float dt = fmaf(q[r].x, p[c].x,
                          fmaf(q[r].y, p[c].y,
                           fmaf(q[r].z, p[c].z, q[r].w * p[c].w)));
        const float d  = fminf(fabsf(dt), 0.999999f);   // clip(|dot|, 1-1e-6)
        const float sq = __builtin_amdgcn_sqrtf(1.0f - d);
        const float pl = fmaf(fmaf(fmaf(A3, d, A2), d, A1), d, A0);
        v[c] = fmaf(sq, -pl, h[c]);    // h - (C/eps)*log2e
      }
      const float cm = fmaxf(fmaxf(v[0], v[1]), fmaxf(v[2], v[3]));
      const float mn = fmaxf(m[r], cm);
      ac[r] = ac[r] * __builtin_amdgcn_exp2f(m[r] - mn)
            + __builtin_amdgcn_exp2f(v[0] - mn) + __builtin_amdgcn_exp2f(v[1] - mn)
            + __builtin_amdgcn_exp2f(v[2] - mn) + __builtin_amdgcn_exp2f(v[3] - mn);
      m[r] = mn;
    }
  }

  // Cross-lane butterfly merge of (m, ac) per row.
  #pragma unroll
  for (int r = 0; r < 4; ++r) {
    #pragma unroll
    for (int off = 32; off >= 1; off >>= 1) {
      const float mo = __shfl_xor(m[r], off, 64);
      const float so = __shfl_xor(ac[r], off, 64);
      const float mn = fmaxf(m[r], mo);
      ac[r] = ac[r] * __builtin_amdgcn_exp2f(m[r] - mn)
            + so   * __builtin_amdgcn_exp2f(mo   - mn);
      m[r] = mn;
    }
  }

  if (lane == 0) {
    const int oidx = s * NPOT + b * NP + i0;
    #pragma unroll
    for (int r = 0; r < 4; ++r) {
      // softmin = -eps * ln2 * (m + log2(sum))
      float res = -eps * 0.69314718055994531f
                * (m[r] + __builtin_amdgcn_logf(ac[r]));
      if (use_avg) res = 0.5f * (pot_old[oidx + r] + res);
      pot_new[oidx + r] = res;
    }
  }
}

__global__ __launch_bounds__(256) void loss_kernel(
    const float* __restrict__ pot, const float* __restrict__ wx,
    const float* __restrict__ wy, float* __restrict__ out)
{
  const int tid = threadIdx.x;
  double acc = 0.0;
  for (int idx = tid; idx < NPOT; idx += 256) {
    acc += (double)wx[idx] * ((double)pot[0 * NPOT + idx] - (double)pot[2 * NPOT + idx]);
    acc += (double)wy[idx] * ((double)pot[1 * NPOT + idx] - (double)pot[3 * NPOT + idx]);
  }
  #pragma unroll
  for (int off = 32; off >= 1; off >>= 1)
    acc += __shfl_xor(acc, off, 64);
  __shared__ double wsum[4];
  if ((tid & 63) == 0) wsum[tid >> 6] = acc;
  __syncthreads();
  if (tid == 0)
    out[0] = (float)((wsum[0] + wsum[1] + wsum[2] + wsum[3]) / (double)BATCH);
}

extern "C" void kernel_launch(void* const* d_in, const int* in_sizes, int n_in,
                              void* d_out, int out_size, void* d_ws, size_t ws_size,
                              hipStream_t stream)
{
  const float* x  = (const float*)d_in[0];
  const float* y  = (const float*)d_in[1];
  const float* wx = (const float*)d_in[2];
  const float* wy = (const float*)d_in[3];

  float* pot[2];
  pot[0] = (float*)d_ws;          // 4 arrays of 16384 floats (256 KB)
  pot[1] = pot[0] + 4 * NPOT;     // ping-pong set (512 KB total, proven safe)

  // geomloss epsilon_schedule(p=2, diameter=3.15, blur=0.01, scaling=0.5)
  double eps_list[16]; int ne = 0;
  eps_list[ne++] = 3.15 * 3.15;
  const double stop = 2.0 * log(0.01), step = 2.0 * log(0.5);
  for (double e = 2.0 * log(3.15); e > stop; e += step) eps_list[ne++] = exp(e);
  eps_list[ne++] = 0.01 * 0.01;   // ne == 11

  const double LOG2E = 1.4426950408889634;
  // acos(d) ~= sqrt(1-d)*(a0 + a1 d + a2 d^2 + a3 d^3), |err| <= 6.7e-5
  const double a0 = 1.5707288, a1 = -0.2121144, a2 = 0.0742610, a3 = -0.0187293;
  const dim3 grid(2048), blkPass(512), blkLoss(256);
  int cur = 0;

  // init pass: h has no potential term (c1 = 0), replace-mode
  {
    const double e = eps_list[0];
    const double sc = 2.0 * LOG2E / e;
    hipLaunchKernelGGL(sink_pass_r4, grid, blkPass, 0, stream,
        x, y, wx, wy, pot[cur], pot[1 - cur],
        (float)e, 0.0f,
        (float)(a0 * sc), (float)(a1 * sc), (float)(a2 * sc), (float)(a3 * sc), 0);
    cur ^= 1;
  }
  // annealing loop over ALL eps in the schedule, averaging update
  for (int k = 0; k < ne; ++k) {
    const double e = eps_list[k];
    const double sc = 2.0 * LOG2E / e;
    hipLaunchKernelGGL(sink_pass_r4, grid, blkPass, 0, stream,
        x, y, wx, wy, pot[cur], pot[1 - cur],
        (float)e, (float)(LOG2E / e),
        (float)(a0 * sc), (float)(a1 * sc), (float)(a2 * sc), (float)(a3 * sc), 1);
    cur ^= 1;
  }
  // final extrapolation at eps = blur^p, replace-mode
  {
    const double e = eps_list[ne - 1];
    const double sc = 2.0 * LOG2E / e;
    hipLaunchKernelGGL(sink_pass_r4, grid, blkPass, 0, stream,
        x, y, wx, wy, pot[cur], pot[1 - cur],
        (float)e, (float)(LOG2E / e),
        (float)(a0 * sc), (float)(a1 * sc), (float)(a2 * sc), (float)(a3 * sc), 0);
    cur ^= 1;
  }

  hipLaunchKernelGGL(loss_kernel, dim3(1), blkLoss, 0, stream,
      pot[cur], wx, wy, (float*)d_out);
}

// Round 7
// 835.376 us; speedup vs baseline: 1.3098x; 1.0745x over previous
//
#include <hip/hip_runtime.h>
#include <math.h>

// Sinkhorn divergence (geomloss 'sinkhorn', debias=True) with quaternion
// geodesic cost, B=8, P=2048, D=4.
//
// R7 = R6's seeded (max-free) softmin + an exact safety net. R6 failed
// because the seed m_hat = -f_prev*log2e/eps has error delta_f*log2e/eps,
// which at tail eps (1e-4) can exceed the fp32 exp2 range -> ss underflowed
// to 0 -> log2(0) = -inf poisoned the potentials. Fix: track mx = max(v)
// during the main loop (1 v_max/elem, off the ss dependency chain), then a
// wave-uniform band check ss in [2^-60, 2^60] (NaN/inf fail too); rows
// outside the band re-sweep the LDS once with the exact m_hat = mx.
// Early/mid passes never trigger; tail passes trigger per-row only on large
// potential drift. 8 rows/wave in SGPRs, grid = 1024 = exactly 4 blocks/CU.
// acos deg-3 poly in u = 1-d (A&S 4.4.45, err 6.7e-5 -> loss err ~3e-4).

#define BATCH 8
#define NP    2048
#define NPOT  (BATCH * NP)   // 16384 floats per potential array

__device__ __forceinline__ float bcastf(float v) {
  return __int_as_float(__builtin_amdgcn_readfirstlane(__float_as_int(v)));
}

__global__ __launch_bounds__(512, 8) void sink_pass_r7(
    const float* __restrict__ x, const float* __restrict__ y,
    const float* __restrict__ wx, const float* __restrict__ wy,
    const float* __restrict__ pot_old, float* __restrict__ pot_new,
    float eps, float c1 /* log2e/eps, 0 on init */,
    float seed_s /* -log2e/eps, 0 on init */,
    float B0, float B1, float B2, float B3 /* acos(u)-poly * 2*log2e/eps */,
    int use_avg)
{
  // grid = 1024 blocks: s (4) x b (8) x rowgroup (32 of 64 rows each).
  const int bid  = blockIdx.x;
  const int s    = bid >> 8;           // 0=f_ba 1=g_ab 2=f_aa 3=g_bb
  const int b    = (bid >> 5) & 7;
  const int rg   = bid & 31;
  const int tid  = threadIdx.x;
  const int lane = tid & 63;

  __shared__ float4 Pts[NP];   // 32 KB
  __shared__ float  Hs[NP];    //  8 KB

  // Stream selection (block-uniform):
  const float4* colp; const float* colw; const float* colpot; const float4* rowp;
  if (s == 0)      { colp=(const float4*)y; colw=wy; colpot=pot_old+1*NPOT; rowp=(const float4*)x; }
  else if (s == 1) { colp=(const float4*)x; colw=wx; colpot=pot_old+0*NPOT; rowp=(const float4*)y; }
  else if (s == 2) { colp=(const float4*)x; colw=wx; colpot=pot_old+2*NPOT; rowp=(const float4*)x; }
  else             { colp=(const float4*)y; colw=wy; colpot=pot_old+3*NPOT; rowp=(const float4*)y; }
  colp += b * NP; colw += b * NP; colpot += b * NP;

  #pragma unroll
  for (int t = 0; t < 4; ++t) {
    const int idx = tid + t * 512;
    Pts[idx] = colp[idx];
    // h_j in log2 domain. c1==0 on init: poison*0 == 0.
    Hs[idx] = fmaf(colpot[idx], c1, __builtin_amdgcn_logf(colw[idx]));
  }
  __syncthreads();

  // This wave's 8 rows; quaternions and m_hat seeds broadcast into SGPRs.
  const int wvu = __builtin_amdgcn_readfirstlane(tid >> 6);
  const int i0  = rg * 64 + wvu * 8;
  const int oidx = s * NPOT + b * NP + i0;
  float qx[8], qy[8], qz[8], qw[8], mh[8];
  #pragma unroll
  for (int r = 0; r < 8; ++r) {
    const float4 t4 = rowp[b * NP + i0 + r];
    qx[r] = bcastf(t4.x); qy[r] = bcastf(t4.y);
    qz[r] = bcastf(t4.z); qw[r] = bcastf(t4.w);
    // m_hat = -f_prev*log2e/eps (log2-domain estimate of this row's lse).
    mh[r] = bcastf(pot_old[oidx + r] * seed_s);
  }

  float ss[8] = {0.f, 0.f, 0.f, 0.f, 0.f, 0.f, 0.f, 0.f};
  float mx[8] = {-3.0e38f, -3.0e38f, -3.0e38f, -3.0e38f,
                 -3.0e38f, -3.0e38f, -3.0e38f, -3.0e38f};

  for (int t = 0; t < 16; ++t) {       // 16 x 2 cols x 64 lanes = 2048 cols
    float4 p[2]; float h[2];
    #pragma unroll
    for (int cc = 0; cc < 2; ++cc) {
      const int j = (t * 2 + cc) * 64 + lane;
      p[cc] = Pts[j];
      h[cc] = Hs[j];
    }
    #pragma unroll
    for (int r = 0; r < 8; ++r) {
      #pragma unroll
      for (int cc = 0; cc < 2; ++cc) {
        const float dt = fmaf(qx[r], p[cc].x,
                          fmaf(qy[r], p[cc].y,
                           fmaf(qz[r], p[cc].z, qw[r] * p[cc].w)));
        const float u  = fmaxf(1.0f - fabsf(dt), 1e-6f);
        const float sq = __builtin_amdgcn_sqrtf(u);
        const float pl = fmaf(fmaf(fmaf(B3, u, B2), u, B1), u, B0);
        const float v  = fmaf(sq, -pl, h[cc]);   // h - (C/eps)*log2e
        mx[r] = fmaxf(mx[r], v);                 // exact max (safety net)
        ss[r] += __builtin_amdgcn_exp2f(v - mh[r]);
      }
    }
  }

  // Butterfly reductions; results bit-identical across lanes.
  #pragma unroll
  for (int r = 0; r < 8; ++r) {
    float sv = ss[r], mv = mx[r];
    #pragma unroll
    for (int off = 32; off >= 1; off >>= 1) {
      sv += __shfl_xor(sv, off, 64);
      mv = fmaxf(mv, __shfl_xor(mv, off, 64));
    }
    ss[r] = sv; mx[r] = mv;
  }

  // Safety net: rows whose seeded sum left the safe band re-sweep with the
  // exact max. Wave-uniform branch (ss/mx uniform post-butterfly).
  #pragma unroll
  for (int r = 0; r < 8; ++r) {
    const bool good = (ss[r] >= 8.6736174e-19f) && (ss[r] <= 1.1529215e18f);
    if (!good) {   // catches underflow, overflow, inf, NaN
      mh[r] = mx[r];
      float sv = 0.0f;
      for (int t = 0; t < 32; ++t) {
        const int j = t * 64 + lane;
        const float4 p = Pts[j];
        const float dt = fmaf(qx[r], p.x,
                          fmaf(qy[r], p.y,
                           fmaf(qz[r], p.z, qw[r] * p.w)));
        const float u  = fmaxf(1.0f - fabsf(dt), 1e-6f);
        const float sq = __builtin_amdgcn_sqrtf(u);
        const float pl = fmaf(fmaf(fmaf(B3, u, B2), u, B1), u, B0);
        const float v  = fmaf(sq, -pl, Hs[j]);
        sv += __builtin_amdgcn_exp2f(v - mh[r]);
      }
      #pragma unroll
      for (int off = 32; off >= 1; off >>= 1)
        sv += __shfl_xor(sv, off, 64);
      ss[r] = sv;
    }
  }

  if (lane == 0) {
    #pragma unroll
    for (int r = 0; r < 8; ++r) {
      // softmin = -eps * ln2 * (m_hat + log2(sum))
      float res = -eps * 0.69314718055994531f
                * (mh[r] + __builtin_amdgcn_logf(ss[r]));
      if (use_avg) res = 0.5f * (pot_old[oidx + r] + res);
      pot_new[oidx + r] = res;
    }
  }
}

__global__ __launch_bounds__(256) void loss_kernel(
    const float* __restrict__ pot, const float* __restrict__ wx,
    const float* __restrict__ wy, float* __restrict__ out)
{
  const int tid = threadIdx.x;
  double acc = 0.0;
  for (int idx = tid; idx < NPOT; idx += 256) {
    acc += (double)wx[idx] * ((double)pot[0 * NPOT + idx] - (double)pot[2 * NPOT + idx]);
    acc += (double)wy[idx] * ((double)pot[1 * NPOT + idx] - (double)pot[3 * NPOT + idx]);
  }
  #pragma unroll
  for (int off = 32; off >= 1; off >>= 1)
    acc += __shfl_xor(acc, off, 64);
  __shared__ double wsum[4];
  if ((tid & 63) == 0) wsum[tid >> 6] = acc;
  __syncthreads();
  if (tid == 0)
    out[0] = (float)((wsum[0] + wsum[1] + wsum[2] + wsum[3]) / (double)BATCH);
}

extern "C" void kernel_launch(void* const* d_in, const int* in_sizes, int n_in,
                              void* d_out, int out_size, void* d_ws, size_t ws_size,
                              hipStream_t stream)
{
  const float* x  = (const float*)d_in[0];
  const float* y  = (const float*)d_in[1];
  const float* wx = (const float*)d_in[2];
  const float* wy = (const float*)d_in[3];

  float* pot[2];
  pot[0] = (float*)d_ws;          // 4 arrays of 16384 floats (256 KB)
  pot[1] = pot[0] + 4 * NPOT;     // ping-pong set (512 KB total, proven safe)

  // geomloss epsilon_schedule(p=2, diameter=3.15, blur=0.01, scaling=0.5)
  double eps_list[16]; int ne = 0;
  eps_list[ne++] = 3.15 * 3.15;
  const double stop = 2.0 * log(0.01), step = 2.0 * log(0.5);
  for (double e = 2.0 * log(3.15); e > stop; e += step) eps_list[ne++] = exp(e);
  eps_list[ne++] = 0.01 * 0.01;   // ne == 11

  const double LOG2E = 1.4426950408889634;
  // acos(d) ~= sqrt(u)*(b0 + b1 u + b2 u^2 + b3 u^3), u = 1-d (A&S 4.4.45
  // re-parameterized), |err| <= 6.7e-5.
  const double b0 = 1.4141461, b1 = 0.1197803, b2 = 0.0180731, b3 = 0.0187293;
  const dim3 grid(1024), blkPass(512), blkLoss(256);
  int cur = 0;

  // init pass: no potential in h, m_hat = 0 (c1 = seed_s = 0), replace-mode
  {
    const double e = eps_list[0];
    const double sc = 2.0 * LOG2E / e;
    hipLaunchKernelGGL(sink_pass_r7, grid, blkPass, 0, stream,
        x, y, wx, wy, pot[cur], pot[1 - cur],
        (float)e, 0.0f, 0.0f,
        (float)(b0 * sc), (float)(b1 * sc), (float)(b2 * sc), (float)(b3 * sc), 0);
    cur ^= 1;
  }
  // annealing loop over ALL eps in the schedule, averaging update
  for (int k = 0; k < ne; ++k) {
    const double e = eps_list[k];
    const double sc = 2.0 * LOG2E / e;
    hipLaunchKernelGGL(sink_pass_r7, grid, blkPass, 0, stream,
        x, y, wx, wy, pot[cur], pot[1 - cur],
        (float)e, (float)(LOG2E / e), (float)(-LOG2E / e),
        (float)(b0 * sc), (float)(b1 * sc), (float)(b2 * sc), (float)(b3 * sc), 1);
    cur ^= 1;
  }
  // final extrapolation at eps = blur^p, replace-mode
  {
    const double e = eps_list[ne - 1];
    const double sc = 2.0 * LOG2E / e;
    hipLaunchKernelGGL(sink_pass_r7, grid, blkPass, 0, stream,
        x, y, wx, wy, pot[cur], pot[1 - cur],
        (float)e, (float)(LOG2E / e), (float)(-LOG2E / e),
        (float)(b0 * sc), (float)(b1 * sc), (float)(b2 * sc), (float)(b3 * sc), 0);
    cur ^= 1;
  }

  hipLaunchKernelGGL(loss_kernel, dim3(1), blkLoss, 0, stream,
      pot[cur], wx, wy, (float*)d_out);
}